// Round 1
// baseline (335.168 us; speedup 1.0000x reference)
//
#include <hip/hip_runtime.h>
#include <math.h>

// Problem constants (b=4, n=m=l=4096, d=512, fft_len=8192, t_len=2l-2=8190)
#define N_FFT   8192
#define LOGN    13
#define SEQ     4096
#define NCH     512
#define TLEN    8190
#define TC_STRIDE 4098   // complex elements per channel in Tc (4097 bins, padded)

__device__ __forceinline__ float2 cmul(float2 a, float2 b) {
    return make_float2(a.x * b.x - a.y * b.y, a.x * b.y + a.y * b.x);
}

// ---------------------------------------------------------------- twiddles ---
// tw[k] = exp(-2*pi*i*k/8192), k in [0, 4096)
__global__ __launch_bounds__(256) void twiddle_init(float2* __restrict__ tw) {
    int k = blockIdx.x * 256 + threadIdx.x;
    double th = -2.0 * 3.14159265358979323846 * (double)k / (double)N_FFT;
    tw[k] = make_float2((float)cos(th), (float)sin(th));
}

// ---------------------------------------------------------------- t spectra --
// One workgroup handles channels d0=2*bid, d1=2*bid+1 packed as one complex FFT.
// Stores Tc[d][k] = (1/8192) * rfft(t_d, 8192)[k]  for k in [0, 4096].
__global__ __launch_bounds__(256) void tfft_kernel(const float* __restrict__ t,
                                                   const float2* __restrict__ tw,
                                                   float2* __restrict__ Tc) {
    __shared__ float2 z[N_FFT];
    const int tid = threadIdx.x;
    const int d0 = blockIdx.x * 2;
    const int d1 = d0 + 1;

    // pack: z[j] = t[j, d0] + i * t[j, d1], zero-padded to 8192
    for (int u = 0; u < 32; ++u) {
        int j = tid + (u << 8);
        float a = 0.f, b = 0.f;
        if (j < TLEN) {
            a = t[(size_t)j * NCH + d0];
            b = t[(size_t)j * NCH + d1];
        }
        z[j] = make_float2(a, b);
    }
    __syncthreads();

    // forward DIF: natural in -> bit-reversed out
    for (int s = LOGN - 1; s >= 0; --s) {
        const int h = 1 << s;
        for (int u = 0; u < 16; ++u) {
            int tt = tid + (u << 8);
            int i = tt & (h - 1);
            int g = tt >> s;
            int p0 = (g << (s + 1)) + i;
            int p1 = p0 + h;
            float2 a = z[p0], b = z[p1];
            float2 w = tw[i << (LOGN - 1 - s)];
            z[p0] = make_float2(a.x + b.x, a.y + b.y);
            float2 dif = make_float2(a.x - b.x, a.y - b.y);
            z[p1] = cmul(dif, w);
        }
        __syncthreads();
    }

    // Hermitian unpack: Z[k] at LDS position brev(k).
    // T0[k] = (Z[k] + conj(Z[-k]))/2,  T1[k] = (Z[k] - conj(Z[-k]))/(2i)
    const float sc = 0.5f / (float)N_FFT;   // fold in ifft 1/N scale
    for (int u = 0; u < 17; ++u) {
        int k = tid + (u << 8);
        if (k > SEQ) break;
        int r1 = __brev((unsigned)k) >> (32 - LOGN);
        int r2 = __brev((unsigned)((N_FFT - k) & (N_FFT - 1))) >> (32 - LOGN);
        float2 A  = z[r1];
        float2 Bc = z[r2];
        float2 Bj = make_float2(Bc.x, -Bc.y);        // conj(Z[-k])
        float2 T0 = make_float2((A.x + Bj.x) * sc, (A.y + Bj.y) * sc);
        float2 dd = make_float2(A.x - Bj.x, A.y - Bj.y);
        float2 T1 = make_float2(dd.y * sc, -dd.x * sc);
        Tc[(size_t)d0 * TC_STRIDE + k] = T0;
        Tc[(size_t)d1 * TC_STRIDE + k] = T1;
    }
}

// ---------------------------------------------------------------- main conv --
// blockIdx.x in [0, 1024): d = bid & 511, pb = bid >> 9 selects batch pair
// (b0=2*pb, b1=2*pb+1). z = x[b0,:,d] + i*x[b1,:,d], fwd FFT, *= T_d, inv FFT,
// out[b0,j,d] = Re z[j], out[b1,j,d] = Im z[j].
__global__ __launch_bounds__(256) void conv_kernel(const float* __restrict__ x,
                                                   const float2* __restrict__ tw,
                                                   const float2* __restrict__ Tc,
                                                   float* __restrict__ out) {
    __shared__ float2 z[N_FFT];
    const int tid = threadIdx.x;
    const int d  = blockIdx.x & (NCH - 1);
    const int pb = blockIdx.x >> 9;

    const float* x0 = x + (size_t)(2 * pb) * SEQ * NCH + d;
    const float* x1 = x0 + (size_t)SEQ * NCH;

    for (int u = 0; u < 16; ++u) {
        int j = tid + (u << 8);
        z[j] = make_float2(x0[(size_t)j * NCH], x1[(size_t)j * NCH]);
        z[j + SEQ] = make_float2(0.f, 0.f);
    }
    __syncthreads();

    // forward DIF
    for (int s = LOGN - 1; s >= 0; --s) {
        const int h = 1 << s;
        for (int u = 0; u < 16; ++u) {
            int tt = tid + (u << 8);
            int i = tt & (h - 1);
            int g = tt >> s;
            int p0 = (g << (s + 1)) + i;
            int p1 = p0 + h;
            float2 a = z[p0], b = z[p1];
            float2 w = tw[i << (LOGN - 1 - s)];
            z[p0] = make_float2(a.x + b.x, a.y + b.y);
            float2 dif = make_float2(a.x - b.x, a.y - b.y);
            z[p1] = cmul(dif, w);
        }
        __syncthreads();
    }

    // pointwise multiply in bit-reversed domain: bin at position r is brev(r)
    const float2* Td = Tc + (size_t)d * TC_STRIDE;
    for (int u = 0; u < 32; ++u) {
        int r = tid + (u << 8);
        int k = __brev((unsigned)r) >> (32 - LOGN);
        float2 T;
        if (k <= SEQ) {
            T = Td[k];
        } else {
            T = Td[N_FFT - k];
            T.y = -T.y;                // conj for upper bins
        }
        z[r] = cmul(z[r], T);
    }
    __syncthreads();

    // inverse DIT (conjugate twiddles): bit-reversed in -> natural out, gain N
    for (int s = 0; s < LOGN; ++s) {
        const int h = 1 << s;
        for (int u = 0; u < 16; ++u) {
            int tt = tid + (u << 8);
            int i = tt & (h - 1);
            int g = tt >> s;
            int p0 = (g << (s + 1)) + i;
            int p1 = p0 + h;
            float2 w = tw[i << (LOGN - 1 - s)];
            float2 wc = make_float2(w.x, -w.y);
            float2 b = cmul(z[p1], wc);
            float2 a = z[p0];
            z[p0] = make_float2(a.x + b.x, a.y + b.y);
            z[p1] = make_float2(a.x - b.x, a.y - b.y);
        }
        __syncthreads();
    }

    // write first 4096 samples
    float* o0 = out + (size_t)(2 * pb) * SEQ * NCH + d;
    float* o1 = o0 + (size_t)SEQ * NCH;
    for (int u = 0; u < 16; ++u) {
        int j = tid + (u << 8);
        float2 v = z[j];
        o0[(size_t)j * NCH] = v.x;
        o1[(size_t)j * NCH] = v.y;
    }
}

extern "C" void kernel_launch(void* const* d_in, const int* in_sizes, int n_in,
                              void* d_out, int out_size, void* d_ws, size_t ws_size,
                              hipStream_t stream) {
    (void)in_sizes; (void)n_in; (void)out_size; (void)ws_size;
    const float* x = (const float*)d_in[0];
    const float* t = (const float*)d_in[1];
    float* out = (float*)d_out;

    float2* tw = (float2*)d_ws;            // 4096 complex = 32 KB
    float2* Tc = tw + 4096;                // 512 * 4098 complex ≈ 16.8 MB

    twiddle_init<<<16, 256, 0, stream>>>(tw);
    tfft_kernel<<<NCH / 2, 256, 0, stream>>>(t, tw, Tc);
    conv_kernel<<<1024, 256, 0, stream>>>(x, tw, Tc, out);
}

// Round 2
// 197.733 us; speedup vs baseline: 1.6950x; 1.6950x over previous
//
#include <hip/hip_runtime.h>
#include <math.h>

// Problem constants (b=4, n=m=l=4096, d=512, fft_len=8192, t_len=2l-2=8190)
#define N_FFT   8192
#define SEQ     4096
#define NCH     512
#define TLEN    8190
#define TC_STRIDE 4098   // complex elements per channel in Tc (4097 bins, padded)

__device__ __forceinline__ float2 cmul(float2 a, float2 b) {
    return make_float2(a.x * b.x - a.y * b.y, a.x * b.y + a.y * b.x);
}
__device__ __forceinline__ float2 cmulj(float2 a, float2 b) {   // a * conj(b)
    return make_float2(a.x * b.x + a.y * b.y, a.y * b.x - a.x * b.y);
}
__device__ __forceinline__ float2 cadd(float2 a, float2 b) {
    return make_float2(a.x + b.x, a.y + b.y);
}
__device__ __forceinline__ float2 csub(float2 a, float2 b) {
    return make_float2(a.x - b.x, a.y - b.y);
}

// W32^j = exp(-2*pi*i*j/32), j in [0,16): real part, imag part
constexpr float W32C[16] = {
    1.0f, 0.9807852804032304f, 0.9238795325112867f, 0.8314696123025452f,
    0.7071067811865476f, 0.5555702330196023f, 0.3826834323650898f, 0.1950903220161283f,
    0.0f, -0.1950903220161282f, -0.3826834323650897f, -0.5555702330196020f,
    -0.7071067811865475f, -0.8314696123025453f, -0.9238795325112867f, -0.9807852804032304f
};
constexpr float W32S[16] = {
    -0.0f, -0.1950903220161283f, -0.3826834323650898f, -0.5555702330196022f,
    -0.7071067811865476f, -0.8314696123025452f, -0.9238795325112867f, -0.9807852804032304f,
    -1.0f, -0.9807852804032304f, -0.9238795325112867f, -0.8314696123025453f,
    -0.7071067811865476f, -0.5555702330196022f, -0.3826834323650899f, -0.1950903220161286f
};

constexpr int BREV5[32] = {0,16,8,24,4,20,12,28,2,18,10,26,6,22,14,30,
                           1,17,9,25,5,21,13,29,3,19,11,27,7,23,15,31};
constexpr int BREV3[8]  = {0,4,2,6,1,5,3,7};

// radix-2 DIF, natural in -> a[j] = A[brev5(j)]
__device__ __forceinline__ void fft32_dif(float2 a[32]) {
#pragma unroll
    for (int s = 4; s >= 0; --s) {
        const int h = 1 << s;
#pragma unroll
        for (int g = 0; g < 32; g += 2 * h) {
#pragma unroll
            for (int i = 0; i < h; ++i) {
                float2 x0 = a[g + i], x1 = a[g + i + h];
                a[g + i] = cadd(x0, x1);
                float2 w = make_float2(W32C[i << (4 - s)], W32S[i << (4 - s)]);
                a[g + i + h] = cmul(csub(x0, x1), w);
            }
        }
    }
}

// radix-2 DIT inverse (W^+, unnormalized): input a[j] = In[brev5(j)] -> natural out
__device__ __forceinline__ void ifft32_dit(float2 a[32]) {
#pragma unroll
    for (int s = 0; s <= 4; ++s) {
        const int h = 1 << s;
#pragma unroll
        for (int g = 0; g < 32; g += 2 * h) {
#pragma unroll
            for (int i = 0; i < h; ++i) {
                float2 w = make_float2(W32C[i << (4 - s)], -W32S[i << (4 - s)]);
                float2 t = cmul(a[g + i + h], w);
                float2 x0 = a[g + i];
                a[g + i] = cadd(x0, t);
                a[g + i + h] = csub(x0, t);
            }
        }
    }
}

__device__ __forceinline__ void fft8_dif(float2 a[8]) {
#pragma unroll
    for (int s = 2; s >= 0; --s) {
        const int h = 1 << s;
#pragma unroll
        for (int g = 0; g < 8; g += 2 * h) {
#pragma unroll
            for (int i = 0; i < h; ++i) {
                float2 x0 = a[g + i], x1 = a[g + i + h];
                a[g + i] = cadd(x0, x1);
                int e = (i << (2 - s)) << 2;   // W8^{i*(4/h)} = W32^{4*...}
                float2 w = make_float2(W32C[e], W32S[e]);
                a[g + i + h] = cmul(csub(x0, x1), w);
            }
        }
    }
}

__device__ __forceinline__ void ifft8_dit(float2 a[8]) {
#pragma unroll
    for (int s = 0; s <= 2; ++s) {
        const int h = 1 << s;
#pragma unroll
        for (int g = 0; g < 8; g += 2 * h) {
#pragma unroll
            for (int i = 0; i < h; ++i) {
                int e = (i << (2 - s)) << 2;
                float2 w = make_float2(W32C[e], -W32S[e]);
                float2 t = cmul(a[g + i + h], w);
                float2 x0 = a[g + i];
                a[g + i] = cadd(x0, t);
                a[g + i + h] = csub(x0, t);
            }
        }
    }
}

// bank-conflict-free LDS slot: logical (row r in [0,32), col c in [0,256))
__device__ __forceinline__ int SLOT(int r, int c) {
    return (r << 8) + (c ^ ((c >> 4) & 7) ^ ((r & 1) << 3));
}

// ---------------------------------------------------------------- twiddles ---
// tw[k] = exp(-2*pi*i*k/8192), k in [0, 8192)
__global__ __launch_bounds__(256) void twiddle_init(float2* __restrict__ tw) {
    int k = blockIdx.x * 256 + threadIdx.x;
    double th = -2.0 * 3.14159265358979323846 * (double)k / (double)N_FFT;
    tw[k] = make_float2((float)cos(th), (float)sin(th));
}

// ---------------------------------------------------------------- t spectra --
// Channels d0=2*bid, d1=2*bid+1 packed as one complex FFT (four-step 32x32x8).
// Stores Tc[d][k] = (1/8192) * rfft(t_d, 8192)[k], k in [0, 4096].
__global__ __launch_bounds__(256) void tfft_kernel(const float* __restrict__ t,
                                                   const float2* __restrict__ tw,
                                                   float2* __restrict__ Tc) {
    __shared__ float2 z[N_FFT];
    const int tid = threadIdx.x;
    const int d0 = blockIdx.x * 2;
    const int d1 = d0 + 1;

    float2 a[32];
    // step A: load column tid (n = 256*n1 + tid), radix-32 FFT, twiddle, store
#pragma unroll
    for (int n1 = 0; n1 < 32; ++n1) {
        int n = (n1 << 8) + tid;
        float va = 0.f, vb = 0.f;
        if (n < TLEN) {
            va = t[(size_t)n * NCH + d0];
            vb = t[(size_t)n * NCH + d1];
        }
        a[n1] = make_float2(va, vb);
    }
    fft32_dif(a);
#pragma unroll
    for (int j = 0; j < 32; ++j) {
        int k1 = BREV5[j];
        float2 v = k1 ? cmul(a[j], tw[(tid * k1) & (N_FFT - 1)]) : a[j];
        z[SLOT(k1, tid)] = v;
    }
    __syncthreads();

    // step B: per-row (r = tid>>3) FFT over n1' (stride 8), offset n2'' = tid&7
    {
        const int r = tid >> 3, n2p = tid & 7;
#pragma unroll
        for (int n1p = 0; n1p < 32; ++n1p)
            a[n1p] = z[SLOT(r, (n1p << 3) + n2p)];
        fft32_dif(a);
#pragma unroll
        for (int j = 0; j < 32; ++j) {
            int k1p = BREV5[j];
            float2 v = k1p ? cmul(a[j], tw[(n2p * k1p) << 5]) : a[j];
            z[SLOT(r, (k1p << 3) + n2p)] = v;
        }
    }
    __syncthreads();

    // step C: 8-point FFTs over contiguous groups
#pragma unroll
    for (int u = 0; u < 4; ++u) {
        int f = tid + (u << 8);
        int k1 = f >> 5, k1p = f & 31;
        float2 b[8];
#pragma unroll
        for (int e = 0; e < 8; ++e) b[e] = z[SLOT(k1, (k1p << 3) + e)];
        fft8_dif(b);
#pragma unroll
        for (int j = 0; j < 8; ++j) z[SLOT(k1, (k1p << 3) + j)] = b[j];
        // slot (k1, 8*k1p + j) now holds bin k = k1 + 32*k1p + 1024*brev3(j)
    }
    __syncthreads();

    // Hermitian unpack: T0[k] = (Z[k]+conj(Z[-k]))/2, T1[k] = (Z[k]-conj(Z[-k]))/(2i)
    const float sc = 0.5f / (float)N_FFT;   // fold in ifft 1/N
    for (int v = 0; v < 17; ++v) {
        int k = tid + (v << 8);
        if (k > SEQ) break;
        int km = (N_FFT - k) & (N_FFT - 1);
        // slot of bin q: row q&31, col 8*((q>>5)&31) + ((q>>10)&7) ... but col
        // e-index stores brev3: bin k = k1 + 32*k1p + 1024*brev3(j) -> j s.t.
        // brev3(j) = k>>10, i.e. j = brev3(k>>10).
        int k1 = k & 31, k1p = (k >> 5) & 31, e = BREV3[(k >> 10) & 7];
        float2 A = z[SLOT(k1, (k1p << 3) + e)];
        int m1 = km & 31, m1p = (km >> 5) & 31, em = BREV3[(km >> 10) & 7];
        float2 B = z[SLOT(m1, (m1p << 3) + em)];
        float2 Bj = make_float2(B.x, -B.y);
        float2 T0 = make_float2((A.x + Bj.x) * sc, (A.y + Bj.y) * sc);
        float2 dd = csub(A, Bj);
        float2 T1 = make_float2(dd.y * sc, -dd.x * sc);
        Tc[(size_t)d0 * TC_STRIDE + k] = T0;
        Tc[(size_t)d1 * TC_STRIDE + k] = T1;
    }
}

// ---------------------------------------------------------------- main conv --
// One block per (channel d, batch pair pb). z = x[b0,:,d] + i*x[b1,:,d];
// four-step forward FFT, pointwise * T_d (Hermitian-folded), exact inverse.
__global__ __launch_bounds__(256) void conv_kernel(const float* __restrict__ x,
                                                   const float2* __restrict__ tw,
                                                   const float2* __restrict__ Tc,
                                                   float* __restrict__ out) {
    __shared__ float2 z[N_FFT];
    const int tid = threadIdx.x;
    // XCD swizzle: contiguous 128-channel chunks per XCD
    const int sb = (blockIdx.x & 7) * 128 + (blockIdx.x >> 3);
    const int d  = sb & (NCH - 1);
    const int pb = sb >> 9;

    const float* x0 = x + (size_t)(2 * pb) * SEQ * NCH + d;
    const float* x1 = x0 + (size_t)SEQ * NCH;

    float2 a[32];
    // ---- step A: global -> regs (column tid), FFT32, twiddle, -> LDS
#pragma unroll
    for (int n1 = 0; n1 < 16; ++n1) {
        int n = (n1 << 8) + tid;     // n < 4096
        a[n1] = make_float2(x0[(size_t)n * NCH], x1[(size_t)n * NCH]);
    }
#pragma unroll
    for (int n1 = 16; n1 < 32; ++n1) a[n1] = make_float2(0.f, 0.f);
    fft32_dif(a);
#pragma unroll
    for (int j = 0; j < 32; ++j) {
        int k1 = BREV5[j];
        float2 v = k1 ? cmul(a[j], tw[(tid * k1) & (N_FFT - 1)]) : a[j];
        z[SLOT(k1, tid)] = v;
    }
    __syncthreads();

    // ---- step B
    {
        const int r = tid >> 3, n2p = tid & 7;
#pragma unroll
        for (int n1p = 0; n1p < 32; ++n1p)
            a[n1p] = z[SLOT(r, (n1p << 3) + n2p)];
        fft32_dif(a);
#pragma unroll
        for (int j = 0; j < 32; ++j) {
            int k1p = BREV5[j];
            float2 v = k1p ? cmul(a[j], tw[(n2p * k1p) << 5]) : a[j];
            z[SLOT(r, (k1p << 3) + n2p)] = v;
        }
    }
    __syncthreads();

    // ---- step C fwd + pointwise + step C inverse (fused, same slots)
    const float2* Td = Tc + (size_t)d * TC_STRIDE;
#pragma unroll
    for (int u = 0; u < 4; ++u) {
        int f = tid + (u << 8);
        int k1 = f >> 5, k1p = f & 31;
        float2 b[8];
#pragma unroll
        for (int e = 0; e < 8; ++e) b[e] = z[SLOT(k1, (k1p << 3) + e)];
        fft8_dif(b);
#pragma unroll
        for (int j = 0; j < 8; ++j) {
            int k = k1 + (k1p << 5) + (BREV3[j] << 10);
            float2 T;
            if (k <= SEQ) T = Td[k];
            else { T = Td[N_FFT - k]; T.y = -T.y; }
            b[j] = cmul(b[j], T);
        }
        ifft8_dit(b);   // DIF output order == DIT input order: no permute
#pragma unroll
        for (int e = 0; e < 8; ++e) z[SLOT(k1, (k1p << 3) + e)] = b[e];
    }
    __syncthreads();

    // ---- step B inverse: un-twiddle, IFFT32 over k1'
    {
        const int r = tid >> 3, n2p = tid & 7;
#pragma unroll
        for (int j = 0; j < 32; ++j) {
            int k1p = BREV5[j];
            float2 v = z[SLOT(r, (k1p << 3) + n2p)];
            a[j] = k1p ? cmulj(v, tw[(n2p * k1p) << 5]) : v;
        }
        ifft32_dit(a);
#pragma unroll
        for (int n1p = 0; n1p < 32; ++n1p)
            z[SLOT(r, (n1p << 3) + n2p)] = a[n1p];
    }
    __syncthreads();

    // ---- step A inverse: un-twiddle, IFFT32 over k1, regs -> global
    {
#pragma unroll
        for (int j = 0; j < 32; ++j) {
            int k1 = BREV5[j];
            float2 v = z[SLOT(k1, tid)];
            a[j] = k1 ? cmulj(v, tw[(tid * k1) & (N_FFT - 1)]) : v;
        }
        ifft32_dit(a);   // a[n1] = output sample n = 256*n1 + tid (x 8192, folded in Tc)
        float* o0 = out + (size_t)(2 * pb) * SEQ * NCH + d;
        float* o1 = o0 + (size_t)SEQ * NCH;
#pragma unroll
        for (int n1 = 0; n1 < 16; ++n1) {
            int n = (n1 << 8) + tid;
            o0[(size_t)n * NCH] = a[n1].x;
            o1[(size_t)n * NCH] = a[n1].y;
        }
    }
}

extern "C" void kernel_launch(void* const* d_in, const int* in_sizes, int n_in,
                              void* d_out, int out_size, void* d_ws, size_t ws_size,
                              hipStream_t stream) {
    (void)in_sizes; (void)n_in; (void)out_size; (void)ws_size;
    const float* x = (const float*)d_in[0];
    const float* t = (const float*)d_in[1];
    float* out = (float*)d_out;

    float2* tw = (float2*)d_ws;            // 8192 complex = 64 KB
    float2* Tc = tw + N_FFT;               // 512 * 4098 complex ≈ 16.8 MB

    twiddle_init<<<N_FFT / 256, 256, 0, stream>>>(tw);
    tfft_kernel<<<NCH / 2, 256, 0, stream>>>(t, tw, Tc);
    conv_kernel<<<1024, 256, 0, stream>>>(x, tw, Tc, out);
}

// Round 3
// 142.368 us; speedup vs baseline: 2.3542x; 1.3889x over previous
//
#include <hip/hip_runtime.h>
#include <math.h>

// Problem constants (b=4, n=m=l=4096, d=512, fft_len=8192, t_len=2l-2=8190)
#define N_FFT   8192
#define SEQ     4096
#define NCH     512
#define TLEN    8190
#define TC_STRIDE 4098   // compact-layout stride (fallback path)

__device__ __forceinline__ float2 cmul(float2 a, float2 b) {
    return make_float2(a.x * b.x - a.y * b.y, a.x * b.y + a.y * b.x);
}
__device__ __forceinline__ float2 cmulj(float2 a, float2 b) {   // a * conj(b)
    return make_float2(a.x * b.x + a.y * b.y, a.y * b.x - a.x * b.y);
}
__device__ __forceinline__ float2 cadd(float2 a, float2 b) {
    return make_float2(a.x + b.x, a.y + b.y);
}
__device__ __forceinline__ float2 csub(float2 a, float2 b) {
    return make_float2(a.x - b.x, a.y - b.y);
}

// W32^j = exp(-2*pi*i*j/32), j in [0,16)
constexpr float W32C[16] = {
    1.0f, 0.9807852804032304f, 0.9238795325112867f, 0.8314696123025452f,
    0.7071067811865476f, 0.5555702330196023f, 0.3826834323650898f, 0.1950903220161283f,
    0.0f, -0.1950903220161282f, -0.3826834323650897f, -0.5555702330196020f,
    -0.7071067811865475f, -0.8314696123025453f, -0.9238795325112867f, -0.9807852804032304f
};
constexpr float W32S[16] = {
    -0.0f, -0.1950903220161283f, -0.3826834323650898f, -0.5555702330196022f,
    -0.7071067811865476f, -0.8314696123025452f, -0.9238795325112867f, -0.9807852804032304f,
    -1.0f, -0.9807852804032304f, -0.9238795325112867f, -0.8314696123025453f,
    -0.7071067811865476f, -0.5555702330196022f, -0.3826834323650899f, -0.1950903220161286f
};

constexpr int BREV5[32] = {0,16,8,24,4,20,12,28,2,18,10,26,6,22,14,30,
                           1,17,9,25,5,21,13,29,3,19,11,27,7,23,15,31};
constexpr int BREV3[8]  = {0,4,2,6,1,5,3,7};

__device__ __forceinline__ int brev3i(int b) {
    return ((b & 1) << 2) | (b & 2) | ((b & 4) >> 2);
}

// radix-2 DIF, natural in -> a[j] = A[brev5(j)]
__device__ __forceinline__ void fft32_dif(float2 a[32]) {
#pragma unroll
    for (int s = 4; s >= 0; --s) {
        const int h = 1 << s;
#pragma unroll
        for (int g = 0; g < 32; g += 2 * h) {
#pragma unroll
            for (int i = 0; i < h; ++i) {
                float2 x0 = a[g + i], x1 = a[g + i + h];
                a[g + i] = cadd(x0, x1);
                float2 w = make_float2(W32C[i << (4 - s)], W32S[i << (4 - s)]);
                a[g + i + h] = cmul(csub(x0, x1), w);
            }
        }
    }
}

// same, but inputs a[16..31] are known zero (zero-padded upper half)
__device__ __forceinline__ void fft32_dif_zpad(float2 a[32]) {
#pragma unroll
    for (int i = 0; i < 16; ++i)   // stage s=4 with x1 = 0
        a[i + 16] = cmul(a[i], make_float2(W32C[i], W32S[i]));
#pragma unroll
    for (int s = 3; s >= 0; --s) {
        const int h = 1 << s;
#pragma unroll
        for (int g = 0; g < 32; g += 2 * h) {
#pragma unroll
            for (int i = 0; i < h; ++i) {
                float2 x0 = a[g + i], x1 = a[g + i + h];
                a[g + i] = cadd(x0, x1);
                float2 w = make_float2(W32C[i << (4 - s)], W32S[i << (4 - s)]);
                a[g + i + h] = cmul(csub(x0, x1), w);
            }
        }
    }
}

// radix-2 DIT inverse (W^+, unnormalized): input a[j] = In[brev5(j)] -> natural
__device__ __forceinline__ void ifft32_dit(float2 a[32]) {
#pragma unroll
    for (int s = 0; s <= 4; ++s) {
        const int h = 1 << s;
#pragma unroll
        for (int g = 0; g < 32; g += 2 * h) {
#pragma unroll
            for (int i = 0; i < h; ++i) {
                float2 w = make_float2(W32C[i << (4 - s)], -W32S[i << (4 - s)]);
                float2 t = cmul(a[g + i + h], w);
                float2 x0 = a[g + i];
                a[g + i] = cadd(x0, t);
                a[g + i + h] = csub(x0, t);
            }
        }
    }
}

__device__ __forceinline__ void fft8_dif(float2 a[8]) {
#pragma unroll
    for (int s = 2; s >= 0; --s) {
        const int h = 1 << s;
#pragma unroll
        for (int g = 0; g < 8; g += 2 * h) {
#pragma unroll
            for (int i = 0; i < h; ++i) {
                float2 x0 = a[g + i], x1 = a[g + i + h];
                a[g + i] = cadd(x0, x1);
                int e = (i << (2 - s)) << 2;   // W8^m = W32^{4m}
                float2 w = make_float2(W32C[e], W32S[e]);
                a[g + i + h] = cmul(csub(x0, x1), w);
            }
        }
    }
}

__device__ __forceinline__ void ifft8_dit(float2 a[8]) {
#pragma unroll
    for (int s = 0; s <= 2; ++s) {
        const int h = 1 << s;
#pragma unroll
        for (int g = 0; g < 8; g += 2 * h) {
#pragma unroll
            for (int i = 0; i < h; ++i) {
                int e = (i << (2 - s)) << 2;
                float2 w = make_float2(W32C[e], -W32S[e]);
                float2 t = cmul(a[g + i + h], w);
                float2 x0 = a[g + i];
                a[g + i] = cadd(x0, t);
                a[g + i + h] = csub(x0, t);
            }
        }
    }
}

// bank-conflict-free LDS slot: logical (row r in [0,32), col c in [0,256))
__device__ __forceinline__ int SLOT(int r, int c) {
    return (r << 8) + (c ^ ((c >> 4) & 7) ^ ((r & 1) << 3));
}
// LDS slot of frequency bin q after forward stage C
__device__ __forceinline__ int ZADDR(int q) {
    return SLOT(q & 31, (((q >> 5) & 31) << 3) + brev3i((q >> 10) & 7));
}

// ---------------------------------------------------------------- twiddles ---
__global__ __launch_bounds__(256) void twiddle_init(float2* __restrict__ tw) {
    int k = blockIdx.x * 256 + threadIdx.x;
    double th = -2.0 * 3.14159265358979323846 * (double)k / (double)N_FFT;
    tw[k] = make_float2((float)cos(th), (float)sin(th));
}

// ---------------------------------------------------------------- t spectra --
// Channels d0=2*bid, d1=2*bid+1 packed as one complex FFT (four-step 32x32x8).
// FULL=1: store full 8192-bin spectrum per channel in conv slot order.
// FULL=0: store bins 0..4096 compact (fallback when ws is small).
template<bool FULL>
__global__ __launch_bounds__(256) void tfft_kernel(const float* __restrict__ t,
                                                   const float2* __restrict__ tw,
                                                   float2* __restrict__ Tc) {
    __shared__ float2 z[N_FFT];
    const int tid = threadIdx.x;
    const int d0 = blockIdx.x * 2;
    const int d1 = d0 + 1;

    float2 a[32];
#pragma unroll
    for (int n1 = 0; n1 < 32; ++n1) {
        int n = (n1 << 8) + tid;
        float va = 0.f, vb = 0.f;
        if (n < TLEN) {
            va = t[(size_t)n * NCH + d0];
            vb = t[(size_t)n * NCH + d1];
        }
        a[n1] = make_float2(va, vb);
    }
    fft32_dif(a);
    {   // store + twiddle w^k1, w = tw[tid]; even/odd incremental chains
        float2 w = tw[tid], w2 = cmul(w, w);
        float2 we = make_float2(1.f, 0.f), wo = w;
#pragma unroll
        for (int k1 = 0; k1 < 32; k1 += 2) {
            z[SLOT(k1, tid)]     = (k1 == 0) ? a[0] : cmul(a[BREV5[k1]], we);
            z[SLOT(k1 + 1, tid)] = cmul(a[BREV5[k1 + 1]], wo);
            we = cmul(we, w2); wo = cmul(wo, w2);
        }
    }
    __syncthreads();

    {   // step B
        const int r = tid >> 3, n2p = tid & 7;
#pragma unroll
        for (int n1p = 0; n1p < 32; ++n1p)
            a[n1p] = z[SLOT(r, (n1p << 3) + n2p)];
        fft32_dif(a);
        float2 wb = tw[n2p << 5], wb2 = cmul(wb, wb);
        float2 be = make_float2(1.f, 0.f), bo = wb;
#pragma unroll
        for (int k1p = 0; k1p < 32; k1p += 2) {
            z[SLOT(r, (k1p << 3) + n2p)]       = (k1p == 0) ? a[0] : cmul(a[BREV5[k1p]], be);
            z[SLOT(r, ((k1p + 1) << 3) + n2p)] = cmul(a[BREV5[k1p + 1]], bo);
            be = cmul(be, wb2); bo = cmul(bo, wb2);
        }
    }
    __syncthreads();

    // step C: 8-point FFTs
#pragma unroll
    for (int u = 0; u < 4; ++u) {
        int f = tid + (u << 8);
        int k1 = f >> 5, k1p = f & 31;
        float2 b[8];
#pragma unroll
        for (int e = 0; e < 8; ++e) b[e] = z[SLOT(k1, (k1p << 3) + e)];
        fft8_dif(b);
#pragma unroll
        for (int j = 0; j < 8; ++j) z[SLOT(k1, (k1p << 3) + j)] = b[j];
        // slot (k1, 8*k1p + j) holds bin k1 + 32*k1p + 1024*brev3(j)
    }
    __syncthreads();

    // Hermitian unpack: T0[k]=(Z[k]+conj(Z[-k]))/2, T1[k]=(Z[k]-conj(Z[-k]))/(2i)
    const float sc = 0.5f / (float)N_FFT;   // fold in ifft 1/N
    if constexpr (FULL) {
#pragma unroll
        for (int v = 0; v < 32; ++v) {
            int s = tid + (v << 8);   // slot index in conv consumption order
            int k = (s >> 8) + (((s >> 3) & 31) << 5) + (brev3i(s & 7) << 10);
            int km = (N_FFT - k) & (N_FFT - 1);
            float2 A = z[ZADDR(k)];
            float2 B = z[ZADDR(km)];
            float2 Bj = make_float2(B.x, -B.y);
            float2 T0 = make_float2((A.x + Bj.x) * sc, (A.y + Bj.y) * sc);
            float2 dd = csub(A, Bj);
            float2 T1 = make_float2(dd.y * sc, -dd.x * sc);
            Tc[(size_t)d0 * N_FFT + s] = T0;
            Tc[(size_t)d1 * N_FFT + s] = T1;
        }
    } else {
        for (int v = 0; v < 17; ++v) {
            int k = tid + (v << 8);
            if (k > SEQ) break;
            int km = (N_FFT - k) & (N_FFT - 1);
            float2 A = z[ZADDR(k)];
            float2 B = z[ZADDR(km)];
            float2 Bj = make_float2(B.x, -B.y);
            float2 T0 = make_float2((A.x + Bj.x) * sc, (A.y + Bj.y) * sc);
            float2 dd = csub(A, Bj);
            float2 T1 = make_float2(dd.y * sc, -dd.x * sc);
            Tc[(size_t)d0 * TC_STRIDE + k] = T0;
            Tc[(size_t)d1 * TC_STRIDE + k] = T1;
        }
    }
}

// ---------------------------------------------------------------- main conv --
// One block per (channel d, batch pair pb). z = x[b0,:,d] + i*x[b1,:,d];
// four-step forward FFT, pointwise * T_d, exact inverse.
template<bool FULL>
__global__ __launch_bounds__(256) void conv_kernel(const float* __restrict__ x,
                                                   const float2* __restrict__ tw,
                                                   const float2* __restrict__ Tc,
                                                   float* __restrict__ out) {
    __shared__ float2 z[N_FFT];
    const int tid = threadIdx.x;
    // XCD swizzle; consecutive sb pairs share d (T reuse in same XCD's L2)
    const int sb = (blockIdx.x & 7) * 128 + (blockIdx.x >> 3);
    const int d  = sb >> 1;
    const int pb = sb & 1;

    const float* x0 = x + (size_t)(2 * pb) * SEQ * NCH + d;
    const float* x1 = x0 + (size_t)SEQ * NCH;

    float2 a[32];
    // ---- step A: global -> regs (column tid), FFT32 (zero-padded), -> LDS
#pragma unroll
    for (int n1 = 0; n1 < 16; ++n1) {
        int n = (n1 << 8) + tid;
        a[n1] = make_float2(x0[(size_t)n * NCH], x1[(size_t)n * NCH]);
    }
    fft32_dif_zpad(a);
    {
        float2 w = tw[tid], w2 = cmul(w, w);
        float2 we = make_float2(1.f, 0.f), wo = w;
#pragma unroll
        for (int k1 = 0; k1 < 32; k1 += 2) {
            z[SLOT(k1, tid)]     = (k1 == 0) ? a[0] : cmul(a[BREV5[k1]], we);
            z[SLOT(k1 + 1, tid)] = cmul(a[BREV5[k1 + 1]], wo);
            we = cmul(we, w2); wo = cmul(wo, w2);
        }
    }
    __syncthreads();

    // ---- step B
    {
        const int r = tid >> 3, n2p = tid & 7;
#pragma unroll
        for (int n1p = 0; n1p < 32; ++n1p)
            a[n1p] = z[SLOT(r, (n1p << 3) + n2p)];
        fft32_dif(a);
        float2 wb = tw[n2p << 5], wb2 = cmul(wb, wb);
        float2 be = make_float2(1.f, 0.f), bo = wb;
#pragma unroll
        for (int k1p = 0; k1p < 32; k1p += 2) {
            z[SLOT(r, (k1p << 3) + n2p)]       = (k1p == 0) ? a[0] : cmul(a[BREV5[k1p]], be);
            z[SLOT(r, ((k1p + 1) << 3) + n2p)] = cmul(a[BREV5[k1p + 1]], bo);
            be = cmul(be, wb2); bo = cmul(bo, wb2);
        }
    }
    __syncthreads();

    // ---- step C fwd + pointwise + step C inverse (fused, same slots)
#pragma unroll
    for (int u = 0; u < 4; ++u) {
        int f = tid + (u << 8);
        int k1 = f >> 5, k1p = f & 31;
        float2 b[8];
#pragma unroll
        for (int e = 0; e < 8; ++e) b[e] = z[SLOT(k1, (k1p << 3) + e)];
        fft8_dif(b);
        if constexpr (FULL) {
            // 8 consecutive complex bins, coalesced float4 loads
            const float4* tp = (const float4*)(Tc + ((size_t)d << 13) + ((size_t)f << 3));
            float4 q0 = tp[0], q1 = tp[1], q2 = tp[2], q3 = tp[3];
            float2 T[8] = { make_float2(q0.x,q0.y), make_float2(q0.z,q0.w),
                            make_float2(q1.x,q1.y), make_float2(q1.z,q1.w),
                            make_float2(q2.x,q2.y), make_float2(q2.z,q2.w),
                            make_float2(q3.x,q3.y), make_float2(q3.z,q3.w) };
#pragma unroll
            for (int j = 0; j < 8; ++j) b[j] = cmul(b[j], T[j]);
        } else {
            const float2* Td = Tc + (size_t)d * TC_STRIDE;
#pragma unroll
            for (int j = 0; j < 8; ++j) {
                int k = k1 + (k1p << 5) + (BREV3[j] << 10);
                float2 T;
                if (k <= SEQ) T = Td[k];
                else { T = Td[N_FFT - k]; T.y = -T.y; }
                b[j] = cmul(b[j], T);
            }
        }
        ifft8_dit(b);
#pragma unroll
        for (int e = 0; e < 8; ++e) z[SLOT(k1, (k1p << 3) + e)] = b[e];
    }
    __syncthreads();

    // ---- step B inverse
    {
        const int r = tid >> 3, n2p = tid & 7;
        float2 wb = tw[n2p << 5], wb2 = cmul(wb, wb);
        float2 be = make_float2(1.f, 0.f), bo = wb;
#pragma unroll
        for (int k1p = 0; k1p < 32; k1p += 2) {
            float2 v0 = z[SLOT(r, (k1p << 3) + n2p)];
            float2 v1 = z[SLOT(r, ((k1p + 1) << 3) + n2p)];
            a[BREV5[k1p]]     = (k1p == 0) ? v0 : cmulj(v0, be);
            a[BREV5[k1p + 1]] = cmulj(v1, bo);
            be = cmul(be, wb2); bo = cmul(bo, wb2);
        }
        ifft32_dit(a);
#pragma unroll
        for (int n1p = 0; n1p < 32; ++n1p)
            z[SLOT(r, (n1p << 3) + n2p)] = a[n1p];
    }
    __syncthreads();

    // ---- step A inverse: un-twiddle, IFFT32, regs -> global
    {
        float2 w = tw[tid], w2 = cmul(w, w);
        float2 we = make_float2(1.f, 0.f), wo = w;
#pragma unroll
        for (int k1 = 0; k1 < 32; k1 += 2) {
            float2 v0 = z[SLOT(k1, tid)];
            float2 v1 = z[SLOT(k1 + 1, tid)];
            a[BREV5[k1]]     = (k1 == 0) ? v0 : cmulj(v0, we);
            a[BREV5[k1 + 1]] = cmulj(v1, wo);
            we = cmul(we, w2); wo = cmul(wo, w2);
        }
        ifft32_dit(a);   // a[n1] = output sample n = 256*n1 + tid
        float* o0 = out + (size_t)(2 * pb) * SEQ * NCH + d;
        float* o1 = o0 + (size_t)SEQ * NCH;
#pragma unroll
        for (int n1 = 0; n1 < 16; ++n1) {
            int n = (n1 << 8) + tid;
            o0[(size_t)n * NCH] = a[n1].x;
            o1[(size_t)n * NCH] = a[n1].y;
        }
    }
}

extern "C" void kernel_launch(void* const* d_in, const int* in_sizes, int n_in,
                              void* d_out, int out_size, void* d_ws, size_t ws_size,
                              hipStream_t stream) {
    (void)in_sizes; (void)n_in; (void)out_size;
    const float* x = (const float*)d_in[0];
    const float* t = (const float*)d_in[1];
    float* out = (float*)d_out;

    float2* tw = (float2*)d_ws;            // 8192 complex = 64 KB
    float2* Tc = tw + N_FFT;

    const size_t need_full = sizeof(float2) * (size_t)N_FFT
                           + sizeof(float2) * (size_t)NCH * N_FFT;   // ~33.6 MB

    twiddle_init<<<N_FFT / 256, 256, 0, stream>>>(tw);
    if (ws_size >= need_full) {
        tfft_kernel<true><<<NCH / 2, 256, 0, stream>>>(t, tw, Tc);
        conv_kernel<true><<<1024, 256, 0, stream>>>(x, tw, Tc, out);
    } else {
        tfft_kernel<false><<<NCH / 2, 256, 0, stream>>>(t, tw, Tc);
        conv_kernel<false><<<1024, 256, 0, stream>>>(x, tw, Tc, out);
    }
}